// Round 10
// baseline (512.104 us; speedup 1.0000x reference)
//
#include <hip/hip_runtime.h>
#include <math.h>

#define BATCH 8
#define SEQ   2048
#define DIM   512

typedef unsigned int u32;
typedef unsigned long long u64;
typedef _Float16 h2  __attribute__((ext_vector_type(2)));
typedef _Float16 h8  __attribute__((ext_vector_type(8)));
typedef float    f4  __attribute__((ext_vector_type(4)));
typedef u32      u4v __attribute__((ext_vector_type(4)));

#define MFMA16(a,b,c) __builtin_amdgcn_mfma_f32_16x16x32_f16((a),(b),(c),0,0,0)

__device__ __forceinline__ void split2(float a, float b, u32& hi, u32& lo) {
    _Float16 ha = (_Float16)a, hb = (_Float16)b;
    h2 th; th[0] = ha; th[1] = hb; hi = __builtin_bit_cast(u32, th);
    h2 tl; tl[0] = (_Float16)(a - (float)ha); tl[1] = (_Float16)(b - (float)hb);
    lo = __builtin_bit_cast(u32, tl);
}
// order-preserving float->u32 (monotone: smaller float -> smaller key)
__device__ __forceinline__ u32 fkey(float f) {
    u32 v = __builtin_bit_cast(u32, f);
    return (v & 0x80000000u) ? ~v : (v | 0x80000000u);
}

// ================= Kernel A: masked-region argmin (3-term f16 MFMA) =================
// Flat job grid: job = (batch, row-group of 64, s-tile of 128) over tiles with
// s_max >= m0 only. 8 waves: wp=w&3 row-group-of-16, h=w>>2 d-half (k-split).
// Maps (R5-R8 validated): A row=lane&15, slot e<->k=8lg+e; B col=lane&15 same;
// C/D row=4lg+reg, col=lane&15.
__global__ __launch_bounds__(512, 2)
void argmin_kernel(const float* __restrict__ Q, const float* __restrict__ K,
                   const int* __restrict__ mfp, u64* __restrict__ ws)
{
    if (mfp[0] == 0) return;   // no mask: kernel B does exact softmax for all rows

    // 128B rows + 16B-granule XOR swizzle (m214 pattern): all LDS ops are b128.
    __shared__ u32 KTh[2][128][32];   // 32 KB  hi f16 pairs, [half][s][d-pair col]
    __shared__ u32 KTl[2][128][32];   // 32 KB  lo
    __shared__ float sx[128][68];     // 34.8 KB  S-exchange, transposed [s][m+pad]

    const int tid  = threadIdx.x;
    const int w    = tid >> 6, wp = w & 3, h = w >> 2;
    const int lane = tid & 63, lx = lane & 15, lg = lane >> 4;

    // ---- job decode: 272 jobs/batch; row-group mg has n = 16-(mg>>1) tiles ----
    int j = blockIdx.x;
    const int b = j / 272; j -= b * 272;
    int mg = 0;
    while (true) { const int n = 16 - (mg >> 1); if (j < n) break; j -= n; mg++; }
    const int m0 = mg * 64;
    const int s0 = (m0 & ~127) + 128 * j;

    const float* __restrict__ Qb = Q + (size_t)b * SEQ * DIM;
    const float* __restrict__ Kb = K + (size_t)b * SEQ * DIM;

    const int krow = (tid >> 1) & 127;   // K staging row
    const int ksc  = tid & 1;            // 32-d subspan of the 64-d chunk

    // ---- Q fragments (own d-half, hi/lo split) ----
    h8 qh[8], ql[8];
    {
        const float* qrowp = Qb + (size_t)(m0 + 16 * wp + lx) * DIM;
        #pragma unroll
        for (int t = 0; t < 8; t++) {
            float bufv[8];
            *(f4*)&bufv[0] = *(const f4*)(qrowp + 256 * h + 32 * t + 8 * lg);
            *(f4*)&bufv[4] = *(const f4*)(qrowp + 256 * h + 32 * t + 8 * lg + 4);
            u4v uh, ul;
            #pragma unroll
            for (int p = 0; p < 4; p++) { u32 hi, lo; split2(bufv[2*p], bufv[2*p+1], hi, lo); uh[p] = hi; ul[p] = lo; }
            qh[t] = __builtin_bit_cast(h8, uh);
            ql[t] = __builtin_bit_cast(h8, ul);
        }
    }

    const f4 fz = {0.f, 0.f, 0.f, 0.f};
    f4 sa[8];
    #pragma unroll
    for (int nt = 0; nt < 8; nt++) sa[nt] = fz;

    f4 kreg[8];
    #pragma unroll
    for (int c = 0; c < 8; c++)
        kreg[c] = *(const f4*)(Kb + (size_t)(s0 + krow) * DIM + 256 * h + 32 * ksc + 4 * c);

    #pragma unroll
    for (int i = 0; i < 4; i++) {
        if (i) __syncthreads();   // prior readers of KT done
        {   // stage 64-d chunk: b128 writes at XOR-swizzled granules
            u32 HH[16], LL[16];
            #pragma unroll
            for (int c = 0; c < 8; c++) {
                split2(kreg[c][0], kreg[c][1], HH[2*c],   LL[2*c]);
                split2(kreg[c][2], kreg[c][3], HH[2*c+1], LL[2*c+1]);
            }
            #pragma unroll
            for (int qd = 0; qd < 4; qd++) {
                const int gp = ((4 * ksc + qd) ^ (krow & 7)) * 4;
                u4v vh = {HH[4*qd], HH[4*qd+1], HH[4*qd+2], HH[4*qd+3]};
                u4v vl = {LL[4*qd], LL[4*qd+1], LL[4*qd+2], LL[4*qd+3]};
                *(u4v*)&KTh[h][krow][gp] = vh;
                *(u4v*)&KTl[h][krow][gp] = vl;
            }
        }
        __syncthreads();          // staged chunk visible
        if (i < 3) {              // register prefetch of next 64-d chunk
            #pragma unroll
            for (int c = 0; c < 8; c++)
                kreg[c] = *(const f4*)(Kb + (size_t)(s0 + krow) * DIM
                                       + 256 * h + 64 * (i + 1) + 32 * ksc + 4 * c);
        }
        __builtin_amdgcn_s_setprio(1);
        #pragma unroll
        for (int tl = 0; tl < 2; tl++) {
            const int t = 2 * i + tl;
            #pragma unroll
            for (int nt = 0; nt < 8; nt++) {
                const int s  = 16 * nt + lx;
                const int gp = ((4 * tl + lg) ^ (s & 7)) * 4;
                const h8 kh = __builtin_bit_cast(h8, *(const u4v*)&KTh[h][s][gp]);
                const h8 kl = __builtin_bit_cast(h8, *(const u4v*)&KTl[h][s][gp]);
                sa[nt] = MFMA16(qh[t], kh, sa[nt]);
                sa[nt] = MFMA16(qh[t], kl, sa[nt]);
                sa[nt] = MFMA16(ql[t], kh, sa[nt]);
            }
        }
        __builtin_amdgcn_s_setprio(0);
    }

    // ---- merge halves (transposed sx, b128) ----
    if (h == 0) {
        #pragma unroll
        for (int nt = 0; nt < 8; nt++)
            *(f4*)&sx[16 * nt + lx][16 * wp + 4 * lg] = sa[nt];
    }
    __syncthreads();

    if (h == 1) {
        #pragma unroll
        for (int nt = 0; nt < 8; nt++) {
            const f4 part = *(const f4*)&sx[16 * nt + lx][16 * wp + 4 * lg];
            #pragma unroll
            for (int r = 0; r < 4; r++) {
                float s = sa[nt][r] + part[r];
                sa[nt][r] = (s == s) ? s : 0.0f;   // NaN scrub (insurance)
            }
        }
        // ---- per-row argmin over masked cols (sg >= tg), then atomicMin ----
        #pragma unroll
        for (int r = 0; r < 4; r++) {
            const int tg = m0 + 16 * wp + 4 * lg + r;
            float mv = INFINITY; int mi = -1;
            #pragma unroll
            for (int nt = 0; nt < 8; nt++) {
                const int sg = s0 + 16 * nt + lx;
                const float v = sa[nt][r];
                if (sg >= tg && v < mv) { mv = v; mi = sg; }
            }
            #pragma unroll
            for (int off = 1; off < 16; off <<= 1) {
                const float ov = __shfl_xor(mv, off);
                const int   oi = __shfl_xor(mi, off);
                if (ov < mv || (ov == mv && oi >= 0 && (mi < 0 || oi < mi))) { mv = ov; mi = oi; }
            }
            if (lx == 0 && mi >= 0) {
                const u64 pk = ((u64)fkey(mv) << 32) | (u32)mi;
                atomicMin(&ws[(size_t)b * SEQ + tg], pk);
            }
        }
    }
}

// ================= Kernel B: gather / exact-softmax fallback =================
__global__ __launch_bounds__(512, 2)
void select_kernel(const float* __restrict__ Q, const float* __restrict__ K,
                   const float* __restrict__ V, const int* __restrict__ mfp,
                   const u64* __restrict__ ws, float* __restrict__ Out)
{
    __shared__ float qrow[DIM];
    __shared__ float zrow[SEQ];
    __shared__ float red[8];
    __shared__ int   flaglist[64];
    __shared__ int   nflag;

    const int tid  = threadIdx.x;
    const int w    = tid >> 6;
    const int lane = tid & 63;
    const int b    = blockIdx.x >> 5;
    const int m0   = (blockIdx.x & 31) * 64;
    const int mf   = mfp[0];
    const float dk = 22.627416997969522f;   // sqrt(512)

    const float* __restrict__ Qb = Q + (size_t)b * SEQ * DIM;
    const float* __restrict__ Kb = K + (size_t)b * SEQ * DIM;
    const float* __restrict__ Vb = V + (size_t)b * SEQ * DIM;
    float* __restrict__ Ob = Out + (size_t)b * SEQ * DIM;

    if (tid == 0) nflag = 0;
    __syncthreads();

    // ---- pure-argmin rows: output = V[s*] exactly (fp32 gather) ----
    #pragma unroll
    for (int rr = 0; rr < 8; rr++) {
        const int tg = m0 + 8 * w + rr;
        const u64 pk = ws[(size_t)b * SEQ + tg];
        const u32 key = (u32)(pk >> 32);
        if (key < 0x80000000u) {   // min masked score < 0: one-hot select
            const int ss = (int)(pk & 0xFFFFFFFFu);
            #pragma unroll
            for (int it = 0; it < 2; it++) {
                const int col = 256 * it + 4 * lane;
                *(f4*)(Ob + (size_t)tg * DIM + col) = *(const f4*)(Vb + (size_t)ss * DIM + col);
            }
        } else if (lane == 0) {    // all masked scores >= 0 (or unwritten): exact path
            const int p = atomicAdd(&nflag, 1);
            flaglist[p] = tg;
        }
    }
    __syncthreads();

    // ---- rare fallback rows: exact fp32 reference softmax over all 2048 cols ----
    const int nf = nflag;
    for (int fi = 0; fi < nf; fi++) {
        const int tg = flaglist[fi];
        if (tid < 128) *(f4*)&qrow[4 * tid] = *(const f4*)(Qb + (size_t)tg * DIM + 4 * tid);
        __syncthreads();

        float z4[4];
        #pragma unroll
        for (int c4 = 0; c4 < 4; c4++) {
            const int col = tid + 512 * c4;
            const float* kr = Kb + (size_t)col * DIM;
            float acc = 0.f;
            for (int d4 = 0; d4 < 128; d4++) {
                const f4 q = *(const f4*)&qrow[4 * d4];
                const f4 k = *(const f4*)(kr + 4 * d4);
                acc += q[0]*k[0] + q[1]*k[1] + q[2]*k[2] + q[3]*k[3];
            }
            const float mult = (mf && col >= tg) ? -1.0e9f : 1.0f;
            z4[c4] = acc * mult / dk;
        }
        // block max
        float lm = fmaxf(fmaxf(z4[0], z4[1]), fmaxf(z4[2], z4[3]));
        #pragma unroll
        for (int off = 1; off < 64; off <<= 1) lm = fmaxf(lm, __shfl_xor(lm, off));
        if (lane == 0) red[w] = lm;
        __syncthreads();
        float M = red[0];
        #pragma unroll
        for (int i = 1; i < 8; i++) M = fmaxf(M, red[i]);
        // exp + block sum
        float ls = 0.f;
        #pragma unroll
        for (int c4 = 0; c4 < 4; c4++) {
            const float p = expf(z4[c4] - M);
            zrow[tid + 512 * c4] = p;
            ls += p;
        }
        #pragma unroll
        for (int off = 1; off < 64; off <<= 1) ls += __shfl_xor(ls, off);
        __syncthreads();   // also orders red reuse
        if (lane == 0) red[w] = ls;
        __syncthreads();
        float L = 0.f;
        #pragma unroll
        for (int i = 0; i < 8; i++) L += red[i];
        // PV: thread owns output column d = tid
        float acc = 0.f;
        for (int s = 0; s < SEQ; s++)
            acc += zrow[s] * Vb[(size_t)s * DIM + tid];
        Ob[(size_t)tg * DIM + tid] = acc / L;
        __syncthreads();
    }
}

extern "C" void kernel_launch(void* const* d_in, const int* in_sizes, int n_in,
                              void* d_out, int out_size, void* d_ws, size_t ws_size,
                              hipStream_t stream) {
    const float* Q  = (const float*)d_in[0];
    const float* K  = (const float*)d_in[1];
    const float* V  = (const float*)d_in[2];
    const int*   mf = (const int*)d_in[3];
    float* O  = (float*)d_out;
    u64*   ws = (u64*)d_ws;

    // init argmin workspace to +inf keys (0xFF.. = maximal)
    hipMemsetAsync(ws, 0xFF, (size_t)BATCH * SEQ * sizeof(u64), stream);

    argmin_kernel<<<dim3(BATCH * 272), dim3(512), 0, stream>>>(Q, K, mf, ws);
    select_kernel<<<dim3(BATCH * (SEQ / 64)), dim3(512), 0, stream>>>(Q, K, V, mf, ws, O);
}

// Round 11
// 343.176 us; speedup vs baseline: 1.4922x; 1.4922x over previous
//
#include <hip/hip_runtime.h>
#include <math.h>

#define BATCH 8
#define SEQ   2048
#define DIM   512

typedef unsigned int u32;
typedef unsigned long long u64;
typedef _Float16 h2  __attribute__((ext_vector_type(2)));
typedef _Float16 h8  __attribute__((ext_vector_type(8)));
typedef float    f4  __attribute__((ext_vector_type(4)));
typedef u32      u4v __attribute__((ext_vector_type(4)));

#define MFMA16(a,b,c) __builtin_amdgcn_mfma_f32_16x16x32_f16((a),(b),(c),0,0,0)

__device__ __forceinline__ void split2(float a, float b, u32& hi, u32& lo) {
    _Float16 ha = (_Float16)a, hb = (_Float16)b;
    h2 th; th[0] = ha; th[1] = hb; hi = __builtin_bit_cast(u32, th);
    h2 tl; tl[0] = (_Float16)(a - (float)ha); tl[1] = (_Float16)(b - (float)hb);
    lo = __builtin_bit_cast(u32, tl);
}
// order-preserving float->u32 (monotone: smaller float -> smaller key)
__device__ __forceinline__ u32 fkey(float f) {
    u32 v = __builtin_bit_cast(u32, f);
    return (v & 0x80000000u) ? ~v : (v | 0x80000000u);
}

// ================= Kernel A: masked-region argmin (R9-verbatim) =================
__global__ __launch_bounds__(512, 2)
void argmin_kernel(const float* __restrict__ Q, const float* __restrict__ K,
                   const int* __restrict__ mfp, u64* __restrict__ ws)
{
    if (mfp[0] == 0) return;   // no mask: fallback kernel does exact softmax

    __shared__ u32 KTh[2][128][32];   // 32 KB  hi f16 pairs, [half][s][d-pair col]
    __shared__ u32 KTl[2][128][32];   // 32 KB  lo
    __shared__ float sx[128][68];     // 34.8 KB  S-exchange, transposed [s][m+pad]

    const int tid  = threadIdx.x;
    const int w    = tid >> 6, wp = w & 3, h = w >> 2;
    const int lane = tid & 63, lx = lane & 15, lg = lane >> 4;

    // job decode: 272 jobs/batch; row-group mg has n = 16-(mg>>1) tiles
    int j = blockIdx.x;
    const int b = j / 272; j -= b * 272;
    int mg = 0;
    while (true) { const int n = 16 - (mg >> 1); if (j < n) break; j -= n; mg++; }
    const int m0 = mg * 64;
    const int s0 = (m0 & ~127) + 128 * j;

    const float* __restrict__ Qb = Q + (size_t)b * SEQ * DIM;
    const float* __restrict__ Kb = K + (size_t)b * SEQ * DIM;

    const int krow = (tid >> 1) & 127;
    const int ksc  = tid & 1;

    h8 qh[8], ql[8];
    {
        const float* qrowp = Qb + (size_t)(m0 + 16 * wp + lx) * DIM;
        #pragma unroll
        for (int t = 0; t < 8; t++) {
            float bufv[8];
            *(f4*)&bufv[0] = *(const f4*)(qrowp + 256 * h + 32 * t + 8 * lg);
            *(f4*)&bufv[4] = *(const f4*)(qrowp + 256 * h + 32 * t + 8 * lg + 4);
            u4v uh, ul;
            #pragma unroll
            for (int p = 0; p < 4; p++) { u32 hi, lo; split2(bufv[2*p], bufv[2*p+1], hi, lo); uh[p] = hi; ul[p] = lo; }
            qh[t] = __builtin_bit_cast(h8, uh);
            ql[t] = __builtin_bit_cast(h8, ul);
        }
    }

    const f4 fz = {0.f, 0.f, 0.f, 0.f};
    f4 sa[8];
    #pragma unroll
    for (int nt = 0; nt < 8; nt++) sa[nt] = fz;

    f4 kreg[8];
    #pragma unroll
    for (int c = 0; c < 8; c++)
        kreg[c] = *(const f4*)(Kb + (size_t)(s0 + krow) * DIM + 256 * h + 32 * ksc + 4 * c);

    #pragma unroll
    for (int i = 0; i < 4; i++) {
        if (i) __syncthreads();
        {
            u32 HH[16], LL[16];
            #pragma unroll
            for (int c = 0; c < 8; c++) {
                split2(kreg[c][0], kreg[c][1], HH[2*c],   LL[2*c]);
                split2(kreg[c][2], kreg[c][3], HH[2*c+1], LL[2*c+1]);
            }
            #pragma unroll
            for (int qd = 0; qd < 4; qd++) {
                const int gp = ((4 * ksc + qd) ^ (krow & 7)) * 4;
                u4v vh = {HH[4*qd], HH[4*qd+1], HH[4*qd+2], HH[4*qd+3]};
                u4v vl = {LL[4*qd], LL[4*qd+1], LL[4*qd+2], LL[4*qd+3]};
                *(u4v*)&KTh[h][krow][gp] = vh;
                *(u4v*)&KTl[h][krow][gp] = vl;
            }
        }
        __syncthreads();
        if (i < 3) {
            #pragma unroll
            for (int c = 0; c < 8; c++)
                kreg[c] = *(const f4*)(Kb + (size_t)(s0 + krow) * DIM
                                       + 256 * h + 64 * (i + 1) + 32 * ksc + 4 * c);
        }
        __builtin_amdgcn_s_setprio(1);
        #pragma unroll
        for (int tl = 0; tl < 2; tl++) {
            const int t = 2 * i + tl;
            #pragma unroll
            for (int nt = 0; nt < 8; nt++) {
                const int s  = 16 * nt + lx;
                const int gp = ((4 * tl + lg) ^ (s & 7)) * 4;
                const h8 kh = __builtin_bit_cast(h8, *(const u4v*)&KTh[h][s][gp]);
                const h8 kl = __builtin_bit_cast(h8, *(const u4v*)&KTl[h][s][gp]);
                sa[nt] = MFMA16(qh[t], kh, sa[nt]);
                sa[nt] = MFMA16(qh[t], kl, sa[nt]);
                sa[nt] = MFMA16(ql[t], kh, sa[nt]);
            }
        }
        __builtin_amdgcn_s_setprio(0);
    }

    if (h == 0) {
        #pragma unroll
        for (int nt = 0; nt < 8; nt++)
            *(f4*)&sx[16 * nt + lx][16 * wp + 4 * lg] = sa[nt];
    }
    __syncthreads();

    if (h == 1) {
        #pragma unroll
        for (int nt = 0; nt < 8; nt++) {
            const f4 part = *(const f4*)&sx[16 * nt + lx][16 * wp + 4 * lg];
            #pragma unroll
            for (int r = 0; r < 4; r++) {
                float s = sa[nt][r] + part[r];
                sa[nt][r] = (s == s) ? s : 0.0f;
            }
        }
        #pragma unroll
        for (int r = 0; r < 4; r++) {
            const int tg = m0 + 16 * wp + 4 * lg + r;
            float mv = INFINITY; int mi = -1;
            #pragma unroll
            for (int nt = 0; nt < 8; nt++) {
                const int sg = s0 + 16 * nt + lx;
                const float v = sa[nt][r];
                if (sg >= tg && v < mv) { mv = v; mi = sg; }
            }
            #pragma unroll
            for (int off = 1; off < 16; off <<= 1) {
                const float ov = __shfl_xor(mv, off);
                const int   oi = __shfl_xor(mi, off);
                if (ov < mv || (ov == mv && oi >= 0 && (mi < 0 || oi < mi))) { mv = ov; mi = oi; }
            }
            if (lx == 0 && mi >= 0) {
                const u64 pk = ((u64)fkey(mv) << 32) | (u32)mi;
                atomicMin(&ws[(size_t)b * SEQ + tg], pk);
            }
        }
    }
}

// ================= Kernel B1: gather + worklist build =================
__global__ __launch_bounds__(512, 2)
void gather_kernel(const float* __restrict__ V, const u64* __restrict__ keys,
                   u32* __restrict__ cnt, u32* __restrict__ list,
                   float* __restrict__ Out)
{
    const int tid  = threadIdx.x;
    const int w    = tid >> 6;
    const int lane = tid & 63;
    const int b    = blockIdx.x >> 5;
    const int m0   = (blockIdx.x & 31) * 64;

    const float* __restrict__ Vb = V + (size_t)b * SEQ * DIM;
    float* __restrict__ Ob = Out + (size_t)b * SEQ * DIM;

    #pragma unroll
    for (int rr = 0; rr < 8; rr++) {
        const int tg = m0 + 8 * w + rr;
        const u64 pk = keys[(size_t)b * SEQ + tg];
        const u32 key = (u32)(pk >> 32);
        if (key < 0x80000000u) {   // min masked score < 0: one-hot select (exact)
            const int ss = (int)(pk & 0xFFFFFFFFu);
            #pragma unroll
            for (int it = 0; it < 2; it++) {
                const int col = 256 * it + 4 * lane;
                *(f4*)(Ob + (size_t)tg * DIM + col) = *(const f4*)(Vb + (size_t)ss * DIM + col);
            }
        } else if (lane == 0) {    // all masked scores >= 0 (or mf==0): exact path
            const u32 p = atomicAdd(cnt, 1u);
            list[p] = ((u32)b << 16) | (u32)tg;
        }
    }
}

// ================= Kernel B2: exact fp32 softmax rows (parallel over blocks) =================
__global__ __launch_bounds__(512, 2)
void fallback_kernel(const float* __restrict__ Q, const float* __restrict__ K,
                     const float* __restrict__ V, const int* __restrict__ mfp,
                     const u32* __restrict__ cnt, const u32* __restrict__ list,
                     float* __restrict__ Out)
{
    __shared__ float qrow[DIM];
    __shared__ float zrow[SEQ];
    __shared__ float red[8];
    __shared__ f4    pacc[4][128];

    const int tid  = threadIdx.x;
    const int w    = tid >> 6;
    const int lane = tid & 63;
    const int mf   = mfp[0];
    const float dk = 22.627416997969522f;   // sqrt(512)

    const int n = (int)cnt[0];
    for (int idx = blockIdx.x; idx < n; idx += gridDim.x) {
        const u32 e  = list[idx];
        const int b  = (int)(e >> 16);
        const int tg = (int)(e & 0xFFFFu);

        const float* __restrict__ Qb = Q + (size_t)b * SEQ * DIM;
        const float* __restrict__ Kb = K + (size_t)b * SEQ * DIM;
        const float* __restrict__ Vb = V + (size_t)b * SEQ * DIM;
        float* __restrict__ Ob = Out + (size_t)b * SEQ * DIM;

        if (tid < 128) *(f4*)&qrow[4 * tid] = *(const f4*)(Qb + (size_t)tg * DIM + 4 * tid);
        __syncthreads();

        // scores for 4 cols per thread (exact fp32 reference formula)
        float z4[4];
        #pragma unroll
        for (int c4 = 0; c4 < 4; c4++) {
            const int col = tid + 512 * c4;
            const float* kr = Kb + (size_t)col * DIM;
            float acc = 0.f;
            #pragma unroll 4
            for (int d4 = 0; d4 < 128; d4++) {
                const f4 q = *(const f4*)&qrow[4 * d4];
                const f4 k = *(const f4*)(kr + 4 * d4);
                acc += q[0]*k[0] + q[1]*k[1] + q[2]*k[2] + q[3]*k[3];
            }
            const float mult = (mf && col >= tg) ? -1.0e9f : 1.0f;
            z4[c4] = acc * mult / dk;
        }
        // block max
        float lm = fmaxf(fmaxf(z4[0], z4[1]), fmaxf(z4[2], z4[3]));
        #pragma unroll
        for (int off = 1; off < 64; off <<= 1) lm = fmaxf(lm, __shfl_xor(lm, off));
        if (lane == 0) red[w] = lm;
        __syncthreads();
        float M = red[0];
        #pragma unroll
        for (int i = 1; i < 8; i++) M = fmaxf(M, red[i]);
        // exp + block sum
        float ls = 0.f;
        #pragma unroll
        for (int c4 = 0; c4 < 4; c4++) {
            const float p = expf(z4[c4] - M);
            zrow[tid + 512 * c4] = p;
            ls += p;
        }
        #pragma unroll
        for (int off = 1; off < 64; off <<= 1) ls += __shfl_xor(ls, off);
        __syncthreads();   // red reads done before overwrite
        if (lane == 0) red[w] = ls;
        __syncthreads();
        float L = 0.f;
        #pragma unroll
        for (int i = 0; i < 8; i++) L += red[i];

        // PV: 4-way s-split, f4 d-columns, LDS partial reduce
        const int dq  = tid & 127;   // d-quad: cols 4dq..4dq+3
        const int sq  = tid >> 7;    // s-quarter
        f4 acc = {0.f, 0.f, 0.f, 0.f};
        const int sbeg = 512 * sq;
        #pragma unroll 8
        for (int s = 0; s < 512; s++)
            acc += zrow[sbeg + s] * *(const f4*)(Vb + (size_t)(sbeg + s) * DIM + 4 * dq);
        pacc[sq][dq] = acc;
        __syncthreads();
        if (tid < 128) {
            f4 r = pacc[0][tid] + pacc[1][tid] + pacc[2][tid] + pacc[3][tid];
            const float il = 1.0f / L;
            r[0] *= il; r[1] *= il; r[2] *= il; r[3] *= il;
            *(f4*)(Ob + (size_t)tg * DIM + 4 * tid) = r;
        }
        __syncthreads();   // LDS reuse safe for next row
    }
}

extern "C" void kernel_launch(void* const* d_in, const int* in_sizes, int n_in,
                              void* d_out, int out_size, void* d_ws, size_t ws_size,
                              hipStream_t stream) {
    const float* Q  = (const float*)d_in[0];
    const float* K  = (const float*)d_in[1];
    const float* V  = (const float*)d_in[2];
    const int*   mf = (const int*)d_in[3];
    float* O   = (float*)d_out;
    u64*   keys = (u64*)d_ws;
    u32*   cnt  = (u32*)((char*)d_ws + (size_t)BATCH * SEQ * sizeof(u64));
    u32*   list = cnt + 1;

    hipMemsetAsync(keys, 0xFF, (size_t)BATCH * SEQ * sizeof(u64), stream);
    hipMemsetAsync(cnt, 0, sizeof(u32), stream);

    argmin_kernel<<<dim3(BATCH * 272), dim3(512), 0, stream>>>(Q, K, mf, keys);
    gather_kernel<<<dim3(BATCH * (SEQ / 64)), dim3(512), 0, stream>>>(V, keys, cnt, list, O);
    fallback_kernel<<<dim3(128), dim3(512), 0, stream>>>(Q, K, V, mf, cnt, list, O);
}

// Round 12
// 203.552 us; speedup vs baseline: 2.5158x; 1.6859x over previous
//
#include <hip/hip_runtime.h>
#include <math.h>

#define BATCH 8
#define SEQ   2048
#define DIM   512
#define NCH   16      // s-chunks per fallback row
#define CHW   128     // chunk width
#define CAP   512     // fallback work-item capacity (CAP/NCH = 32 rows fast-path)

typedef unsigned int u32;
typedef unsigned long long u64;
typedef _Float16 h2  __attribute__((ext_vector_type(2)));
typedef _Float16 h8  __attribute__((ext_vector_type(8)));
typedef float    f4  __attribute__((ext_vector_type(4)));
typedef u32      u4v __attribute__((ext_vector_type(4)));

#define MFMA16(a,b,c) __builtin_amdgcn_mfma_f32_16x16x32_f16((a),(b),(c),0,0,0)

__device__ __forceinline__ void split2(float a, float b, u32& hi, u32& lo) {
    _Float16 ha = (_Float16)a, hb = (_Float16)b;
    h2 th; th[0] = ha; th[1] = hb; hi = __builtin_bit_cast(u32, th);
    h2 tl; tl[0] = (_Float16)(a - (float)ha); tl[1] = (_Float16)(b - (float)hb);
    lo = __builtin_bit_cast(u32, tl);
}
// order-preserving float->u32 (monotone)
__device__ __forceinline__ u32 fkey(float f) {
    u32 v = __builtin_bit_cast(u32, f);
    return (v & 0x80000000u) ? ~v : (v | 0x80000000u);
}

// ================= Kernel A: masked-region argmin (R9/R10-verbatim) =================
__global__ __launch_bounds__(512, 2)
void argmin_kernel(const float* __restrict__ Q, const float* __restrict__ K,
                   const int* __restrict__ mfp, u64* __restrict__ ws)
{
    if (mfp[0] == 0) return;

    __shared__ u32 KTh[2][128][32];
    __shared__ u32 KTl[2][128][32];
    __shared__ float sx[128][68];

    const int tid  = threadIdx.x;
    const int w    = tid >> 6, wp = w & 3, h = w >> 2;
    const int lane = tid & 63, lx = lane & 15, lg = lane >> 4;

    int j = blockIdx.x;
    const int b = j / 272; j -= b * 272;
    int mg = 0;
    while (true) { const int n = 16 - (mg >> 1); if (j < n) break; j -= n; mg++; }
    const int m0 = mg * 64;
    const int s0 = (m0 & ~127) + 128 * j;

    const float* __restrict__ Qb = Q + (size_t)b * SEQ * DIM;
    const float* __restrict__ Kb = K + (size_t)b * SEQ * DIM;

    const int krow = (tid >> 1) & 127;
    const int ksc  = tid & 1;

    h8 qh[8], ql[8];
    {
        const float* qrowp = Qb + (size_t)(m0 + 16 * wp + lx) * DIM;
        #pragma unroll
        for (int t = 0; t < 8; t++) {
            float bufv[8];
            *(f4*)&bufv[0] = *(const f4*)(qrowp + 256 * h + 32 * t + 8 * lg);
            *(f4*)&bufv[4] = *(const f4*)(qrowp + 256 * h + 32 * t + 8 * lg + 4);
            u4v uh, ul;
            #pragma unroll
            for (int p = 0; p < 4; p++) { u32 hi, lo; split2(bufv[2*p], bufv[2*p+1], hi, lo); uh[p] = hi; ul[p] = lo; }
            qh[t] = __builtin_bit_cast(h8, uh);
            ql[t] = __builtin_bit_cast(h8, ul);
        }
    }

    const f4 fz = {0.f, 0.f, 0.f, 0.f};
    f4 sa[8];
    #pragma unroll
    for (int nt = 0; nt < 8; nt++) sa[nt] = fz;

    f4 kreg[8];
    #pragma unroll
    for (int c = 0; c < 8; c++)
        kreg[c] = *(const f4*)(Kb + (size_t)(s0 + krow) * DIM + 256 * h + 32 * ksc + 4 * c);

    #pragma unroll
    for (int i = 0; i < 4; i++) {
        if (i) __syncthreads();
        {
            u32 HH[16], LL[16];
            #pragma unroll
            for (int c = 0; c < 8; c++) {
                split2(kreg[c][0], kreg[c][1], HH[2*c],   LL[2*c]);
                split2(kreg[c][2], kreg[c][3], HH[2*c+1], LL[2*c+1]);
            }
            #pragma unroll
            for (int qd = 0; qd < 4; qd++) {
                const int gp = ((4 * ksc + qd) ^ (krow & 7)) * 4;
                u4v vh = {HH[4*qd], HH[4*qd+1], HH[4*qd+2], HH[4*qd+3]};
                u4v vl = {LL[4*qd], LL[4*qd+1], LL[4*qd+2], LL[4*qd+3]};
                *(u4v*)&KTh[h][krow][gp] = vh;
                *(u4v*)&KTl[h][krow][gp] = vl;
            }
        }
        __syncthreads();
        if (i < 3) {
            #pragma unroll
            for (int c = 0; c < 8; c++)
                kreg[c] = *(const f4*)(Kb + (size_t)(s0 + krow) * DIM
                                       + 256 * h + 64 * (i + 1) + 32 * ksc + 4 * c);
        }
        __builtin_amdgcn_s_setprio(1);
        #pragma unroll
        for (int tl = 0; tl < 2; tl++) {
            const int t = 2 * i + tl;
            #pragma unroll
            for (int nt = 0; nt < 8; nt++) {
                const int s  = 16 * nt + lx;
                const int gp = ((4 * tl + lg) ^ (s & 7)) * 4;
                const h8 kh = __builtin_bit_cast(h8, *(const u4v*)&KTh[h][s][gp]);
                const h8 kl = __builtin_bit_cast(h8, *(const u4v*)&KTl[h][s][gp]);
                sa[nt] = MFMA16(qh[t], kh, sa[nt]);
                sa[nt] = MFMA16(qh[t], kl, sa[nt]);
                sa[nt] = MFMA16(ql[t], kh, sa[nt]);
            }
        }
        __builtin_amdgcn_s_setprio(0);
    }

    if (h == 0) {
        #pragma unroll
        for (int nt = 0; nt < 8; nt++)
            *(f4*)&sx[16 * nt + lx][16 * wp + 4 * lg] = sa[nt];
    }
    __syncthreads();

    if (h == 1) {
        #pragma unroll
        for (int nt = 0; nt < 8; nt++) {
            const f4 part = *(const f4*)&sx[16 * nt + lx][16 * wp + 4 * lg];
            #pragma unroll
            for (int r = 0; r < 4; r++) {
                float s = sa[nt][r] + part[r];
                sa[nt][r] = (s == s) ? s : 0.0f;
            }
        }
        #pragma unroll
        for (int r = 0; r < 4; r++) {
            const int tg = m0 + 16 * wp + 4 * lg + r;
            float mv = INFINITY; int mi = -1;
            #pragma unroll
            for (int nt = 0; nt < 8; nt++) {
                const int sg = s0 + 16 * nt + lx;
                const float v = sa[nt][r];
                if (sg >= tg && v < mv) { mv = v; mi = sg; }
            }
            #pragma unroll
            for (int off = 1; off < 16; off <<= 1) {
                const float ov = __shfl_xor(mv, off);
                const int   oi = __shfl_xor(mi, off);
                if (ov < mv || (ov == mv && oi >= 0 && (mi < 0 || oi < mi))) { mv = ov; mi = oi; }
            }
            if (lx == 0 && mi >= 0) {
                const u64 pk = ((u64)fkey(mv) << 32) | (u32)mi;
                atomicMin(&ws[(size_t)b * SEQ + tg], pk);
            }
        }
    }
}

// ================= Kernel B1: gather + worklist (R10-verbatim) =================
__global__ __launch_bounds__(512, 2)
void gather_kernel(const float* __restrict__ V, const u64* __restrict__ keys,
                   u32* __restrict__ cnt, u32* __restrict__ list,
                   float* __restrict__ Out)
{
    const int tid  = threadIdx.x;
    const int w    = tid >> 6;
    const int lane = tid & 63;
    const int b    = blockIdx.x >> 5;
    const int m0   = (blockIdx.x & 31) * 64;

    const float* __restrict__ Vb = V + (size_t)b * SEQ * DIM;
    float* __restrict__ Ob = Out + (size_t)b * SEQ * DIM;

    #pragma unroll
    for (int rr = 0; rr < 8; rr++) {
        const int tg = m0 + 8 * w + rr;
        const u64 pk = keys[(size_t)b * SEQ + tg];
        const u32 key = (u32)(pk >> 32);
        if (key < 0x80000000u) {
            const int ss = (int)(pk & 0xFFFFFFFFu);
            #pragma unroll
            for (int it = 0; it < 2; it++) {
                const int col = 256 * it + 4 * lane;
                *(f4*)(Ob + (size_t)tg * DIM + col) = *(const f4*)(Vb + (size_t)ss * DIM + col);
            }
        } else if (lane == 0) {
            const u32 p = atomicAdd(cnt, 1u);
            list[p] = ((u32)b << 16) | (u32)tg;
        }
    }
}

// ====== Kernel B2a: fallback partials — one (row, s-chunk) per work item ======
__global__ __launch_bounds__(512, 2)
void fb_part_kernel(const float* __restrict__ Q, const float* __restrict__ K,
                    const float* __restrict__ V, const int* __restrict__ mfp,
                    const u32* __restrict__ cnt, const u32* __restrict__ list,
                    float2* __restrict__ meta, float* __restrict__ partials)
{
    __shared__ float qrow[DIM];
    __shared__ float zpart[4][CHW];
    __shared__ float zs[CHW];
    __shared__ float zp[CHW];
    __shared__ f4    pacc[4][128];
    __shared__ float red2[2];

    const int tid = threadIdx.x;
    const int mf  = mfp[0];
    const float dk = 22.627416997969522f;

    const int n  = (int)cnt[0];
    const int nw = min(n * NCH, CAP);

    for (int wi = blockIdx.x; wi < nw; wi += gridDim.x) {
        const int ridx  = wi >> 4;
        const int chunk = wi & 15;
        const u32 e  = list[ridx];
        const int b  = (int)(e >> 16);
        const int tg = (int)(e & 0xFFFFu);

        const float* __restrict__ Qb = Q + (size_t)b * SEQ * DIM;
        const float* __restrict__ Kb = K + (size_t)b * SEQ * DIM;
        const float* __restrict__ Vb = V + (size_t)b * SEQ * DIM;

        if (tid < 128) *(f4*)&qrow[4 * tid] = *(const f4*)(Qb + (size_t)tg * DIM + 4 * tid);
        __syncthreads();

        // ---- QK for 128 cols of this chunk: (col j, d-quarter dseg) ----
        {
            const int jj   = tid & 127;
            const int dseg = tid >> 7;
            const int col  = chunk * CHW + jj;
            const float* kr = Kb + (size_t)col * DIM + 128 * dseg;
            float acc = 0.f;
            #pragma unroll 8
            for (int d4 = 0; d4 < 32; d4++) {
                const f4 q = *(const f4*)&qrow[4 * (32 * dseg + d4)];
                const f4 k = *(const f4*)(kr + 4 * d4);
                acc += q[0]*k[0] + q[1]*k[1] + q[2]*k[2] + q[3]*k[3];
            }
            zpart[dseg][jj] = acc;
        }
        __syncthreads();
        if (tid < 128) {
            const int col = chunk * CHW + tid;
            float z = zpart[0][tid] + zpart[1][tid] + zpart[2][tid] + zpart[3][tid];
            const float mult = (mf && col >= tg) ? -1.0e9f : 1.0f;
            zs[tid] = z * mult / dk;
        }
        __syncthreads();
        // chunk max (wave0)
        if (tid < 64) {
            float m = fmaxf(zs[tid], zs[tid + 64]);
            #pragma unroll
            for (int off = 1; off < 64; off <<= 1) m = fmaxf(m, __shfl_xor(m, off));
            if (tid == 0) red2[0] = m;
        }
        __syncthreads();
        const float M = red2[0];
        if (tid < 128) zp[tid] = expf(zs[tid] - M);
        __syncthreads();
        if (tid < 64) {
            float s = zp[tid] + zp[tid + 64];
            #pragma unroll
            for (int off = 1; off < 64; off <<= 1) s += __shfl_xor(s, off);
            if (tid == 0) red2[1] = s;
        }
        // ---- PV partial numerator over this chunk's 128 s ----
        {
            const int dq   = tid & 127;
            const int sseg = tid >> 7;
            f4 acc = {0.f, 0.f, 0.f, 0.f};
            const int sb = chunk * CHW + 32 * sseg;
            #pragma unroll 8
            for (int s = 0; s < 32; s++)
                acc += zp[32 * sseg + s] * *(const f4*)(Vb + (size_t)(sb + s) * DIM + 4 * dq);
            pacc[sseg][dq] = acc;
        }
        __syncthreads();
        if (tid < 128) {
            const f4 nc = pacc[0][tid] + pacc[1][tid] + pacc[2][tid] + pacc[3][tid];
            *(f4*)&partials[(size_t)wi * DIM + 4 * tid] = nc;
        }
        if (tid == 0) meta[wi] = make_float2(M, red2[1]);
        __syncthreads();   // LDS safe for next iteration
    }
}

// ====== Kernel B2b: combine chunk partials (LSE merge); slow path beyond CAP ======
__global__ __launch_bounds__(512, 2)
void fb_combine_kernel(const float* __restrict__ Q, const float* __restrict__ K,
                       const float* __restrict__ V, const int* __restrict__ mfp,
                       const u32* __restrict__ cnt, const u32* __restrict__ list,
                       const float2* __restrict__ meta, const float* __restrict__ partials,
                       float* __restrict__ Out)
{
    __shared__ float qrow[DIM];
    __shared__ float zrow[SEQ];
    __shared__ float red[8];
    __shared__ f4    pacc[4][128];

    const int tid  = threadIdx.x;
    const int w    = tid >> 6;
    const int lane = tid & 63;
    const int mf   = mfp[0];
    const float dk = 22.627416997969522f;

    const int n = (int)cnt[0];
    for (int idx = blockIdx.x; idx < n; idx += gridDim.x) {
        const u32 e  = list[idx];
        const int b  = (int)(e >> 16);
        const int tg = (int)(e & 0xFFFFu);
        float* __restrict__ Ob = Out + (size_t)b * SEQ * DIM;

        if (idx < CAP / NCH) {
            // fast: merge 16 chunk partials (meta reads are wave-broadcast)
            float M = -INFINITY;
            #pragma unroll
            for (int c = 0; c < NCH; c++) M = fmaxf(M, meta[idx * NCH + c].x);
            float L = 0.f, o = 0.f;
            #pragma unroll
            for (int c = 0; c < NCH; c++) {
                const float2 mc = meta[idx * NCH + c];
                const float fct = expf(mc.x - M);
                L += mc.y * fct;
                o += partials[(size_t)(idx * NCH + c) * DIM + tid] * fct;
            }
            Ob[(size_t)tg * DIM + tid] = o / L;
        } else {
            // slow exact path (unreachable for bench data; kept for correctness)
            const float* __restrict__ Qb = Q + (size_t)b * SEQ * DIM;
            const float* __restrict__ Kb = K + (size_t)b * SEQ * DIM;
            const float* __restrict__ Vb = V + (size_t)b * SEQ * DIM;
            if (tid < 128) *(f4*)&qrow[4 * tid] = *(const f4*)(Qb + (size_t)tg * DIM + 4 * tid);
            __syncthreads();
            float z4[4];
            #pragma unroll
            for (int c4 = 0; c4 < 4; c4++) {
                const int col = tid + 512 * c4;
                const float* kr = Kb + (size_t)col * DIM;
                float acc = 0.f;
                #pragma unroll 4
                for (int d4 = 0; d4 < 128; d4++) {
                    const f4 q = *(const f4*)&qrow[4 * d4];
                    const f4 k = *(const f4*)(kr + 4 * d4);
                    acc += q[0]*k[0] + q[1]*k[1] + q[2]*k[2] + q[3]*k[3];
                }
                const float mult = (mf && col >= tg) ? -1.0e9f : 1.0f;
                z4[c4] = acc * mult / dk;
            }
            float lm = fmaxf(fmaxf(z4[0], z4[1]), fmaxf(z4[2], z4[3]));
            #pragma unroll
            for (int off = 1; off < 64; off <<= 1) lm = fmaxf(lm, __shfl_xor(lm, off));
            if (lane == 0) red[w] = lm;
            __syncthreads();
            float M = red[0];
            #pragma unroll
            for (int i = 1; i < 8; i++) M = fmaxf(M, red[i]);
            float ls = 0.f;
            #pragma unroll
            for (int c4 = 0; c4 < 4; c4++) {
                const float p = expf(z4[c4] - M);
                zrow[tid + 512 * c4] = p;
                ls += p;
            }
            #pragma unroll
            for (int off = 1; off < 64; off <<= 1) ls += __shfl_xor(ls, off);
            __syncthreads();
            if (lane == 0) red[w] = ls;
            __syncthreads();
            float L = 0.f;
            #pragma unroll
            for (int i = 0; i < 8; i++) L += red[i];
            const int dq = tid & 127;
            const int sq = tid >> 7;
            f4 acc = {0.f, 0.f, 0.f, 0.f};
            const int sbeg = 512 * sq;
            #pragma unroll 8
            for (int s = 0; s < 512; s++)
                acc += zrow[sbeg + s] * *(const f4*)(Vb + (size_t)(sbeg + s) * DIM + 4 * dq);
            pacc[sq][dq] = acc;
            __syncthreads();
            if (tid < 128) {
                f4 r = pacc[0][tid] + pacc[1][tid] + pacc[2][tid] + pacc[3][tid];
                const float il = 1.0f / L;
                r[0] *= il; r[1] *= il; r[2] *= il; r[3] *= il;
                *(f4*)(Ob + (size_t)tg * DIM + 4 * tid) = r;
            }
            __syncthreads();
        }
    }
}

extern "C" void kernel_launch(void* const* d_in, const int* in_sizes, int n_in,
                              void* d_out, int out_size, void* d_ws, size_t ws_size,
                              hipStream_t stream) {
    const float* Q  = (const float*)d_in[0];
    const float* K  = (const float*)d_in[1];
    const float* V  = (const float*)d_in[2];
    const int*   mf = (const int*)d_in[3];
    float* O = (float*)d_out;

    char* wsb = (char*)d_ws;
    u64*    keys     = (u64*)wsb;                                   // 128 KB
    u32*    cnt      = (u32*)(wsb + 131072);
    u32*    list     = (u32*)(wsb + 131072 + 256);                  // 64 KB
    float2* meta     = (float2*)(wsb + 131072 + 256 + 65536);       // 4 KB
    float*  partials = (float*)(wsb + 131072 + 256 + 65536 + 8192); // 1 MB

    hipMemsetAsync(keys, 0xFF, (size_t)BATCH * SEQ * sizeof(u64), stream);
    hipMemsetAsync(cnt, 0, sizeof(u32), stream);

    argmin_kernel<<<dim3(BATCH * 272), dim3(512), 0, stream>>>(Q, K, mf, keys);
    gather_kernel<<<dim3(BATCH * (SEQ / 64)), dim3(512), 0, stream>>>(V, keys, cnt, list, O);
    fb_part_kernel<<<dim3(512), dim3(512), 0, stream>>>(Q, K, V, mf, cnt, list, meta, partials);
    fb_combine_kernel<<<dim3(128), dim3(512), 0, stream>>>(Q, K, V, mf, cnt, list, meta, partials, O);
}